// Round 1
// baseline (223.786 us; speedup 1.0000x reference)
//
#include <hip/hip_runtime.h>
#include <hip/hip_bf16.h>

// TaylorActivation: out = Horner(x; c[0..8]), c = w[:,0], order 8.
// x: (512, 65536) fp32 -> 33,554,432 elems. Memory-bound elementwise.
// float4 vectorized, exact-cover grid.

__global__ __launch_bounds__(256) void taylor_poly_kernel(
    const float4* __restrict__ x,
    const float*  __restrict__ w,   // 9 coefficients, c[i] = w[i]
    float4* __restrict__ out,
    int n4)
{
    int i = blockIdx.x * blockDim.x + threadIdx.x;
    if (i >= n4) return;

    // Coefficients: tiny, read-only, broadcast across all lanes (L1/L2 hit).
    const float c0 = w[0], c1 = w[1], c2 = w[2], c3 = w[3], c4 = w[4];
    const float c5 = w[5], c6 = w[6], c7 = w[7], c8 = w[8];

    float4 v = x[i];
    float4 r;

    // Horner: r = c8; for k=7..0: r = r*x + c[k]
    r.x = c8; r.y = c8; r.z = c8; r.w = c8;

    r.x = fmaf(r.x, v.x, c7); r.y = fmaf(r.y, v.y, c7); r.z = fmaf(r.z, v.z, c7); r.w = fmaf(r.w, v.w, c7);
    r.x = fmaf(r.x, v.x, c6); r.y = fmaf(r.y, v.y, c6); r.z = fmaf(r.z, v.z, c6); r.w = fmaf(r.w, v.w, c6);
    r.x = fmaf(r.x, v.x, c5); r.y = fmaf(r.y, v.y, c5); r.z = fmaf(r.z, v.z, c5); r.w = fmaf(r.w, v.w, c5);
    r.x = fmaf(r.x, v.x, c4); r.y = fmaf(r.y, v.y, c4); r.z = fmaf(r.z, v.z, c4); r.w = fmaf(r.w, v.w, c4);
    r.x = fmaf(r.x, v.x, c3); r.y = fmaf(r.y, v.y, c3); r.z = fmaf(r.z, v.z, c3); r.w = fmaf(r.w, v.w, c3);
    r.x = fmaf(r.x, v.x, c2); r.y = fmaf(r.y, v.y, c2); r.z = fmaf(r.z, v.z, c2); r.w = fmaf(r.w, v.w, c2);
    r.x = fmaf(r.x, v.x, c1); r.y = fmaf(r.y, v.y, c1); r.z = fmaf(r.z, v.z, c1); r.w = fmaf(r.w, v.w, c1);
    r.x = fmaf(r.x, v.x, c0); r.y = fmaf(r.y, v.y, c0); r.z = fmaf(r.z, v.z, c0); r.w = fmaf(r.w, v.w, c0);

    out[i] = r;
}

extern "C" void kernel_launch(void* const* d_in, const int* in_sizes, int n_in,
                              void* d_out, int out_size, void* d_ws, size_t ws_size,
                              hipStream_t stream) {
    const float* x = (const float*)d_in[0];
    const float* w = (const float*)d_in[1];
    float* out = (float*)d_out;

    int n = in_sizes[0];          // 33,554,432 — divisible by 4
    int n4 = n >> 2;

    const int block = 256;
    int grid = (n4 + block - 1) / block;   // 32768

    taylor_poly_kernel<<<grid, block, 0, stream>>>(
        (const float4*)x, w, (float4*)out, n4);
}

// Round 3
// 220.604 us; speedup vs baseline: 1.0144x; 1.0144x over previous
//
#include <hip/hip_runtime.h>
#include <hip/hip_bf16.h>

// TaylorActivation: out = Horner(x; c[0..8]), c = w[:,0], order 8.
// x: (512, 65536) fp32 = 33,554,432 elems. Pure streaming elementwise ->
// memory-bound. 268 MB total traffic; roofline ~43 us @ 6.3 TB/s.
//
// Each thread: 4x 16B vectors (64 B), block-strided so every access is fully
// coalesced. Nontemporal loads/stores (no reuse -> skip cache allocate).
// NOTE: __builtin_nontemporal_* requires a native clang vector type, not
// HIP_vector_type<float,4> — use ext_vector_type(4).

typedef float f32x4 __attribute__((ext_vector_type(4)));

#define VPT 4  // f32x4 per thread

__global__ __launch_bounds__(256) void taylor_poly_kernel(
    const f32x4* __restrict__ x,
    const float* __restrict__ w,   // 9 coefficients, c[i] = w[i]
    f32x4* __restrict__ out,
    int n4)
{
    const float c0 = w[0], c1 = w[1], c2 = w[2], c3 = w[3], c4 = w[4];
    const float c5 = w[5], c6 = w[6], c7 = w[7], c8 = w[8];

    // Base for this block's 4 consecutive coalesced sweeps.
    int base = blockIdx.x * (blockDim.x * VPT) + threadIdx.x;

    f32x4 v[VPT];
#pragma unroll
    for (int k = 0; k < VPT; ++k) {
        int i = base + k * blockDim.x;
        if (i < n4) v[k] = __builtin_nontemporal_load(&x[i]);
    }

#pragma unroll
    for (int k = 0; k < VPT; ++k) {
        f32x4 r;
#pragma unroll
        for (int e = 0; e < 4; ++e) {
            float xv = v[k][e];
            float acc = fmaf(c8, xv, c7);
            acc = fmaf(acc, xv, c6);
            acc = fmaf(acc, xv, c5);
            acc = fmaf(acc, xv, c4);
            acc = fmaf(acc, xv, c3);
            acc = fmaf(acc, xv, c2);
            acc = fmaf(acc, xv, c1);
            acc = fmaf(acc, xv, c0);
            r[e] = acc;
        }
        v[k] = r;  // reuse register
    }

#pragma unroll
    for (int k = 0; k < VPT; ++k) {
        int i = base + k * blockDim.x;
        if (i < n4) __builtin_nontemporal_store(v[k], &out[i]);
    }
}

extern "C" void kernel_launch(void* const* d_in, const int* in_sizes, int n_in,
                              void* d_out, int out_size, void* d_ws, size_t ws_size,
                              hipStream_t stream) {
    const float* x = (const float*)d_in[0];
    const float* w = (const float*)d_in[1];
    float* out = (float*)d_out;

    int n = in_sizes[0];          // 33,554,432 — divisible by 16
    int n4 = n >> 2;              // 8,388,608 f32x4

    const int block = 256;
    const int elems_per_block = block * VPT;                  // 1024 vec4 / block
    int grid = (n4 + elems_per_block - 1) / elems_per_block;  // 8192

    taylor_poly_kernel<<<grid, block, 0, stream>>>(
        (const f32x4*)x, w, (f32x4*)out, n4);
}